// Round 1
// baseline (166.813 us; speedup 1.0000x reference)
//
#include <hip/hip_runtime.h>
#include <hip/hip_bf16.h>
#include <stdint.h>

typedef __hip_bfloat16 bf16;
typedef __attribute__((ext_vector_type(8))) short short8;
typedef __attribute__((ext_vector_type(4))) float f32x4;

#define MFMA16(A, B, C) __builtin_amdgcn_mfma_f32_16x16x32_bf16(A, B, C, 0, 0, 0)

// ---- constants ----
#define SB 2
#define SS 2048
#define SD 768
#define SH 12
#define SDK 64
#define SM (SB*SS)            // 4096 rows
#define BHSD (SB*SH*SS*SDK)   // 3145728 elems per Q/K/V

__device__ __forceinline__ void gload_lds16(const bf16* g, bf16* l) {
    __builtin_amdgcn_global_load_lds(
        (const __attribute__((address_space(1))) void*)(g),
        (__attribute__((address_space(3))) void*)(l),
        16, 0, 0);
}

// ---- f32 -> bf16 convert, 4 elems/thread ----
__global__ void cvt_f32_bf16_x4(const float4* __restrict__ s, uint64_t* __restrict__ d, int n4) {
    int i = blockIdx.x * blockDim.x + threadIdx.x;
    if (i >= n4) return;
    float4 v = s[i];
    union { bf16 h[4]; uint64_t u; } p;
    p.h[0] = __float2bfloat16(v.x);
    p.h[1] = __float2bfloat16(v.y);
    p.h[2] = __float2bfloat16(v.z);
    p.h[3] = __float2bfloat16(v.w);
    d[i] = p.u;
}

// ---- MFMA GEMM: Y = A[M,K] @ Bw[N,K]^T, 128x128 tile, BK=64 ----
// EPI==0: scatter to Q/K/V (Out = qkv base, N==2304). V stored transposed [bh][dk][s].
// EPI==1: f32 row-major [M,768] to Out.
template<int EPI>
__global__ __launch_bounds__(256) void gemm_bt(const bf16* __restrict__ A,
                                               const bf16* __restrict__ Bw,
                                               void* __restrict__ Out,
                                               int K) {
    __shared__ bf16 lA[128 * 64];
    __shared__ bf16 lB[128 * 64];
    const int tid  = threadIdx.x;
    const int lane = tid & 63;
    const int wid  = tid >> 6;
    const int wr = wid >> 1, wc = wid & 1;
    const int m0 = blockIdx.y * 128, n0 = blockIdx.x * 128;
    const int g = lane >> 4, l15 = lane & 15;
    const int srow = lane >> 3, slot = lane & 7;

    f32x4 acc[4][4] = {};

    for (int kt = 0; kt < K; kt += 64) {
        __syncthreads();
        #pragma unroll
        for (int p = 0; p < 4; ++p) {
            int c = wid * 4 + p;              // chunk 0..15, 8 rows each
            int row = c * 8 + srow;
            int colsw = (slot ^ (row & 7)) * 8;   // pre-swizzled source col
            gload_lds16(A  + (m0 + row) * K + kt + colsw, &lA[c * 512]);
            gload_lds16(Bw + (n0 + row) * K + kt + colsw, &lB[c * 512]);
        }
        __syncthreads();
        #pragma unroll
        for (int ks = 0; ks < 2; ++ks) {
            short8 af[4], bfv[4];
            #pragma unroll
            for (int m = 0; m < 4; ++m) {
                int row = wr * 64 + m * 16 + l15;
                int idx = row * 64 + (((ks * 4 + g) ^ (row & 7)) * 8);
                af[m] = *reinterpret_cast<const short8*>(&lA[idx]);
            }
            #pragma unroll
            for (int n = 0; n < 4; ++n) {
                int row = wc * 64 + n * 16 + l15;
                int idx = row * 64 + (((ks * 4 + g) ^ (row & 7)) * 8);
                bfv[n] = *reinterpret_cast<const short8*>(&lB[idx]);
            }
            #pragma unroll
            for (int m = 0; m < 4; ++m)
                #pragma unroll
                for (int n = 0; n < 4; ++n)
                    acc[m][n] = MFMA16(af[m], bfv[n], acc[m][n]);
        }
    }

    #pragma unroll
    for (int m = 0; m < 4; ++m) {
        #pragma unroll
        for (int n = 0; n < 4; ++n) {
            int col = n0 + wc * 64 + n * 16 + l15;
            #pragma unroll
            for (int r = 0; r < 4; ++r) {
                int row = m0 + wr * 64 + m * 16 + g * 4 + r;
                float v = acc[m][n][r];
                if constexpr (EPI == 0) {
                    int which = (col >= 1536) ? 2 : (col >= 768 ? 1 : 0);
                    int e = col - which * 768;
                    int h = e >> 6, d = e & 63;
                    int b = row >> 11, s = row & 2047;
                    int bh = b * SH + h;
                    bf16* dst = (bf16*)Out;
                    int idx;
                    if (which == 2) idx = 2 * BHSD + (bh * 64 + d) * SS + s;   // V^T [bh][dk][s]
                    else            idx = which * BHSD + (bh * SS + s) * 64 + d;
                    dst[idx] = __float2bfloat16(v);
                } else {
                    ((float*)Out)[row * SD + col] = v;
                }
            }
        }
    }
}

// ---- flash attention: grid (32 qtiles, 24 bh), 4 waves, QBLK=64, KVBLK=64 ----
__global__ __launch_bounds__(256) void attn_kernel(const bf16* __restrict__ Qb,
                                                   const bf16* __restrict__ Kb,
                                                   const bf16* __restrict__ Vtb,
                                                   bf16* __restrict__ AO) {
    __shared__ bf16 lK[64 * 64];
    __shared__ bf16 lV[64 * 64];      // V^T tile: [dk][kv]
    __shared__ bf16 lP[4][16 * 64];   // per-wave P scratch

    const int qt = 31 - blockIdx.x;   // heavy blocks first
    const int bh = blockIdx.y;
    const int b = bh / SH, h = bh - b * SH;
    const int tid = threadIdx.x, lane = tid & 63, w = tid >> 6;
    const int g = lane >> 4, l15 = lane & 15;
    const int q0 = qt * 64;
    const int srow = lane >> 3, slot = lane & 7;
    const float C = 0.18033688011112042f;   // (1/sqrt(64)) * log2(e)

    const bf16* Qh = Qb + bh * SS * 64;
    const bf16* Kh = Kb + bh * SS * 64;
    const bf16* Vh = Vtb + bh * 64 * SS;

    short8 qf[2];
    #pragma unroll
    for (int ks = 0; ks < 2; ++ks)
        qf[ks] = *reinterpret_cast<const short8*>(Qh + (q0 + w * 16 + l15) * 64 + ks * 32 + g * 8);

    f32x4 oacc[4] = {};
    float mrow[4], lrow[4];
    #pragma unroll
    for (int r = 0; r < 4; ++r) { mrow[r] = -1e30f; lrow[r] = 0.f; }

    for (int kt = 0; kt <= qt; ++kt) {
        __syncthreads();
        #pragma unroll
        for (int p = 0; p < 2; ++p) {
            int c = w * 2 + p;               // chunk 0..7, 8 rows each
            int row = c * 8 + srow;
            int colsw = (slot ^ (row & 7)) * 8;
            gload_lds16(Kh + (kt * 64 + row) * 64 + colsw, &lK[c * 512]);
            gload_lds16(Vh + row * SS + kt * 64 + colsw, &lV[c * 512]);
        }
        __syncthreads();

        // S = Q @ K^T   (16 x 64 per wave)
        f32x4 sacc[4] = {};
        #pragma unroll
        for (int ks = 0; ks < 2; ++ks) {
            #pragma unroll
            for (int n = 0; n < 4; ++n) {
                int row = n * 16 + l15;
                int idx = row * 64 + (((ks * 4 + g) ^ (row & 7)) * 8);
                short8 kf = *reinterpret_cast<const short8*>(&lK[idx]);
                sacc[n] = MFMA16(qf[ks], kf, sacc[n]);
            }
        }

        if (kt == qt) {   // diagonal tile: causal mask
            #pragma unroll
            for (int n = 0; n < 4; ++n) {
                int kcol = kt * 64 + n * 16 + l15;
                #pragma unroll
                for (int r = 0; r < 4; ++r) {
                    int qrow = q0 + w * 16 + g * 4 + r;
                    if (kcol > qrow) sacc[n][r] = -1e30f;
                }
            }
        }

        // online softmax
        float pm[4], sf[4], rs[4];
        #pragma unroll
        for (int r = 0; r < 4; ++r) {
            float v = fmaxf(fmaxf(sacc[0][r], sacc[1][r]), fmaxf(sacc[2][r], sacc[3][r]));
            v = fmaxf(v, __shfl_xor(v, 1, 16));
            v = fmaxf(v, __shfl_xor(v, 2, 16));
            v = fmaxf(v, __shfl_xor(v, 4, 16));
            v = fmaxf(v, __shfl_xor(v, 8, 16));
            float mn = fmaxf(mrow[r], v);
            sf[r] = exp2f((mrow[r] - mn) * C);
            mrow[r] = mn;
            pm[r] = mn;
            rs[r] = 0.f;
        }
        #pragma unroll
        for (int n = 0; n < 4; ++n) {
            #pragma unroll
            for (int r = 0; r < 4; ++r) {
                float p = exp2f((sacc[n][r] - pm[r]) * C);
                rs[r] += p;
                int prow = g * 4 + r;
                int sl = (n * 2 + (l15 >> 3)) ^ (prow & 7);   // swizzled 16B slot
                lP[w][prow * 64 + sl * 8 + (l15 & 7)] = __float2bfloat16(p);
            }
        }
        #pragma unroll
        for (int r = 0; r < 4; ++r) {
            rs[r] += __shfl_xor(rs[r], 1, 16);
            rs[r] += __shfl_xor(rs[r], 2, 16);
            rs[r] += __shfl_xor(rs[r], 4, 16);
            rs[r] += __shfl_xor(rs[r], 8, 16);
            lrow[r] = lrow[r] * sf[r] + rs[r];
        }
        #pragma unroll
        for (int n = 0; n < 4; ++n)
            #pragma unroll
            for (int r = 0; r < 4; ++r)
                oacc[n][r] *= sf[r];

        // O += P @ V
        #pragma unroll
        for (int ks = 0; ks < 2; ++ks) {
            int idx = l15 * 64 + (((ks * 4 + g) ^ (l15 & 7)) * 8);
            short8 pa = *reinterpret_cast<const short8*>(&lP[w][idx]);
            #pragma unroll
            for (int n = 0; n < 4; ++n) {
                int vrow = n * 16 + l15;
                int vidx = vrow * 64 + (((ks * 4 + g) ^ (vrow & 7)) * 8);
                short8 vf = *reinterpret_cast<const short8*>(&lV[vidx]);
                oacc[n] = MFMA16(pa, vf, oacc[n]);
            }
        }
    }

    #pragma unroll
    for (int n = 0; n < 4; ++n) {
        int dcol = h * 64 + n * 16 + l15;
        #pragma unroll
        for (int r = 0; r < 4; ++r) {
            int row = b * SS + q0 + w * 16 + g * 4 + r;
            AO[row * SD + dcol] = __float2bfloat16(oacc[n][r] / lrow[r]);
        }
    }
}

extern "C" void kernel_launch(void* const* d_in, const int* in_sizes, int n_in,
                              void* d_out, int out_size, void* d_ws, size_t ws_size,
                              hipStream_t stream) {
    const float* x  = (const float*)d_in[0];
    const float* wq = (const float*)d_in[1];
    const float* wk = (const float*)d_in[2];
    const float* wv = (const float*)d_in[3];
    const float* wo = (const float*)d_in[4];
    float* out = (float*)d_out;

    bf16* xb   = (bf16*)d_ws;              // 3,145,728 elems
    bf16* wqkv = xb + SM * SD;             // 1,769,472
    bf16* wob  = wqkv + 3 * SD * SD;       // 589,824
    bf16* qkv  = wob + SD * SD;            // 3 * 3,145,728 (Q, K, V^T)
    bf16* ao   = qkv + 3 * BHSD;           // 3,145,728
    // total ~36.2 MB of d_ws

    const int NX = SM * SD;        // 3145728
    const int NW = SD * SD;        // 589824
    cvt_f32_bf16_x4<<<NX / 1024, 256, 0, stream>>>((const float4*)x,  (uint64_t*)xb,          NX / 4);
    cvt_f32_bf16_x4<<<NW / 1024, 256, 0, stream>>>((const float4*)wq, (uint64_t*)wqkv,        NW / 4);
    cvt_f32_bf16_x4<<<NW / 1024, 256, 0, stream>>>((const float4*)wk, (uint64_t*)(wqkv + NW), NW / 4);
    cvt_f32_bf16_x4<<<NW / 1024, 256, 0, stream>>>((const float4*)wv, (uint64_t*)(wqkv + 2 * NW), NW / 4);
    cvt_f32_bf16_x4<<<NW / 1024, 256, 0, stream>>>((const float4*)wo, (uint64_t*)wob,         NW / 4);

    gemm_bt<0><<<dim3(2304 / 128, SM / 128), 256, 0, stream>>>(xb, wqkv, (void*)qkv, SD);
    attn_kernel<<<dim3(SS / 64, SB * SH), 256, 0, stream>>>(qkv, qkv + BHSD, qkv + 2 * BHSD, ao);
    gemm_bt<1><<<dim3(SD / 128, SM / 128), 256, 0, stream>>>(ao, wob, (void*)out, SD);
}

// Round 2
// 157.717 us; speedup vs baseline: 1.0577x; 1.0577x over previous
//
#include <hip/hip_runtime.h>
#include <hip/hip_bf16.h>
#include <stdint.h>

typedef __hip_bfloat16 bf16;
typedef __attribute__((ext_vector_type(8))) short short8;
typedef __attribute__((ext_vector_type(4))) float f32x4;

#define MFMA16(A, B, C) __builtin_amdgcn_mfma_f32_16x16x32_bf16(A, B, C, 0, 0, 0)

// ---- constants ----
#define SB 2
#define SS 2048
#define SD 768
#define SH 12
#define SDK 64
#define SM (SB*SS)            // 4096 rows
#define BHSD (SB*SH*SS*SDK)   // 3145728 elems per Q/K/V
// (1/sqrt(64)) * log2(e) folded into Q at projection time -> attn works in exp2 domain
#define QSCALE 0.18033688011112042f

__device__ __forceinline__ void gload_lds16(const bf16* g, bf16* l) {
    __builtin_amdgcn_global_load_lds(
        (const __attribute__((address_space(1))) void*)(g),
        (__attribute__((address_space(3))) void*)(l),
        16, 0, 0);
}

// vmcnt(0) drain + raw barrier + scheduling fence (T3-min 2-phase recipe)
#define BARSYNC() do { \
    asm volatile("s_waitcnt vmcnt(0)" ::: "memory"); \
    __builtin_amdgcn_s_barrier(); \
    __builtin_amdgcn_sched_barrier(0); \
} while (0)

// ---- f32 -> bf16 convert, 4 elems/thread ----
__global__ void cvt_f32_bf16_x4(const float4* __restrict__ s, uint64_t* __restrict__ d, int n4) {
    int i = blockIdx.x * blockDim.x + threadIdx.x;
    if (i >= n4) return;
    float4 v = s[i];
    union { bf16 h[4]; uint64_t u; } p;
    p.h[0] = __float2bfloat16(v.x);
    p.h[1] = __float2bfloat16(v.y);
    p.h[2] = __float2bfloat16(v.z);
    p.h[3] = __float2bfloat16(v.w);
    d[i] = p.u;
}

// ---- MFMA GEMM: Y = A[M,K] @ Bw[N,K]^T, 128x128 tile, BK=64 ----
// EPI==0: scatter to Q/K/V (Out = qkv base, N==2304). V stored transposed [bh][dk][s].
//         Q additionally scaled by QSCALE (softmax works in exp2 domain).
// EPI==1: f32 row-major [M,768] to Out.
template<int EPI>
__global__ __launch_bounds__(256) void gemm_bt(const bf16* __restrict__ A,
                                               const bf16* __restrict__ Bw,
                                               void* __restrict__ Out,
                                               int K) {
    __shared__ bf16 lA[128 * 64];
    __shared__ bf16 lB[128 * 64];
    const int tid  = threadIdx.x;
    const int lane = tid & 63;
    const int wid  = tid >> 6;
    const int wr = wid >> 1, wc = wid & 1;
    const int m0 = blockIdx.y * 128, n0 = blockIdx.x * 128;
    const int g = lane >> 4, l15 = lane & 15;
    const int srow = lane >> 3, slot = lane & 7;

    f32x4 acc[4][4] = {};

    for (int kt = 0; kt < K; kt += 64) {
        __syncthreads();
        #pragma unroll
        for (int p = 0; p < 4; ++p) {
            int c = wid * 4 + p;              // chunk 0..15, 8 rows each
            int row = c * 8 + srow;
            int colsw = (slot ^ (row & 7)) * 8;   // pre-swizzled source col
            gload_lds16(A  + (m0 + row) * K + kt + colsw, &lA[c * 512]);
            gload_lds16(Bw + (n0 + row) * K + kt + colsw, &lB[c * 512]);
        }
        __syncthreads();
        #pragma unroll
        for (int ks = 0; ks < 2; ++ks) {
            short8 af[4], bfv[4];
            #pragma unroll
            for (int m = 0; m < 4; ++m) {
                int row = wr * 64 + m * 16 + l15;
                int idx = row * 64 + (((ks * 4 + g) ^ (row & 7)) * 8);
                af[m] = *reinterpret_cast<const short8*>(&lA[idx]);
            }
            #pragma unroll
            for (int n = 0; n < 4; ++n) {
                int row = wc * 64 + n * 16 + l15;
                int idx = row * 64 + (((ks * 4 + g) ^ (row & 7)) * 8);
                bfv[n] = *reinterpret_cast<const short8*>(&lB[idx]);
            }
            #pragma unroll
            for (int m = 0; m < 4; ++m)
                #pragma unroll
                for (int n = 0; n < 4; ++n)
                    acc[m][n] = MFMA16(af[m], bfv[n], acc[m][n]);
        }
    }

    #pragma unroll
    for (int m = 0; m < 4; ++m) {
        #pragma unroll
        for (int n = 0; n < 4; ++n) {
            int col = n0 + wc * 64 + n * 16 + l15;
            #pragma unroll
            for (int r = 0; r < 4; ++r) {
                int row = m0 + wr * 64 + m * 16 + g * 4 + r;
                float v = acc[m][n][r];
                if constexpr (EPI == 0) {
                    int which = (col >= 1536) ? 2 : (col >= 768 ? 1 : 0);
                    int e = col - which * 768;
                    int h = e >> 6, d = e & 63;
                    int b = row >> 11, s = row & 2047;
                    int bh = b * SH + h;
                    bf16* dst = (bf16*)Out;
                    int idx;
                    if (which == 2) idx = 2 * BHSD + (bh * 64 + d) * SS + s;   // V^T [bh][dk][s]
                    else            idx = which * BHSD + (bh * SS + s) * 64 + d;
                    if (which == 0) v *= QSCALE;
                    dst[idx] = __float2bfloat16(v);
                } else {
                    ((float*)Out)[row * SD + col] = v;
                }
            }
        }
    }
}

// ---- flash attention: 768 blocks (XCD-swizzled), 4 waves, QBLK=64, KVBLK=64 ----
// Double-buffered K/V staging (T3-min 2-phase), defer-max (T13), setprio (T5).
__global__ __launch_bounds__(256) void attn_kernel(const bf16* __restrict__ Qb,
                                                   const bf16* __restrict__ Kb,
                                                   const bf16* __restrict__ Vtb,
                                                   bf16* __restrict__ AO) {
    __shared__ bf16 lK[2][64 * 64];
    __shared__ bf16 lV[2][64 * 64];   // V^T tile: [dk][kv]
    __shared__ bf16 lP[4][16 * 64];   // per-wave P scratch

    // bijective XCD swizzle: 768 = 8 XCDs x 96; same-bh blocks cluster per XCD,
    // heavy q-tiles first within each XCD.
    const int orig = blockIdx.x;
    const int wgid = (orig & 7) * 96 + (orig >> 3);
    const int bh = wgid >> 5;
    const int qt = 31 - (wgid & 31);

    const int b = bh / SH, h = bh - b * SH;
    const int tid = threadIdx.x, lane = tid & 63, w = tid >> 6;
    const int g = lane >> 4, l15 = lane & 15;
    const int q0 = qt * 64;
    const int srow = lane >> 3, slot = lane & 7;

    const bf16* Qh = Qb + bh * SS * 64;
    const bf16* Kh = Kb + bh * SS * 64;
    const bf16* Vh = Vtb + bh * 64 * SS;

    short8 qf[2];
    #pragma unroll
    for (int ks = 0; ks < 2; ++ks)
        qf[ks] = *reinterpret_cast<const short8*>(Qh + (q0 + w * 16 + l15) * 64 + ks * 32 + g * 8);

    f32x4 oacc[4] = {};
    float mrow[4], lrow[4];
    #pragma unroll
    for (int r = 0; r < 4; ++r) { mrow[r] = -1e30f; lrow[r] = 0.f; }

    auto STAGE = [&](int buf, int kt) {
        #pragma unroll
        for (int p = 0; p < 2; ++p) {
            int c = w * 2 + p;               // chunk 0..7, 8 rows each
            int row = c * 8 + srow;
            int colsw = (slot ^ (row & 7)) * 8;
            gload_lds16(Kh + (kt * 64 + row) * 64 + colsw, &lK[buf][c * 512]);
            gload_lds16(Vh + row * SS + kt * 64 + colsw, &lV[buf][c * 512]);
        }
    };

    // prologue: stage tile 0
    STAGE(0, 0);
    BARSYNC();

    int cur = 0;
    for (int kt = 0; kt <= qt; ++kt) {
        // issue next tile's loads FIRST (they fly under this tile's compute)
        if (kt < qt) STAGE(cur ^ 1, kt + 1);

        // S = Q @ K^T   (16 x 64 per wave) — Q pre-scaled, S in exp2 domain
        f32x4 sacc[4] = {};
        __builtin_amdgcn_s_setprio(1);
        #pragma unroll
        for (int ks = 0; ks < 2; ++ks) {
            #pragma unroll
            for (int n = 0; n < 4; ++n) {
                int row = n * 16 + l15;
                int idx = row * 64 + (((ks * 4 + g) ^ (row & 7)) * 8);
                short8 kf = *reinterpret_cast<const short8*>(&lK[cur][idx]);
                sacc[n] = MFMA16(qf[ks], kf, sacc[n]);
            }
        }
        __builtin_amdgcn_s_setprio(0);

        if (kt == qt) {   // diagonal tile: causal mask
            #pragma unroll
            for (int n = 0; n < 4; ++n) {
                int kcol = kt * 64 + n * 16 + l15;
                #pragma unroll
                for (int r = 0; r < 4; ++r) {
                    int qrow = q0 + w * 16 + g * 4 + r;
                    if (kcol > qrow) sacc[n][r] = -1e30f;
                }
            }
        }

        // ---- online softmax (exp2 domain), defer-max THR=8 ----
        float vmax[4];
        #pragma unroll
        for (int r = 0; r < 4; ++r) {
            float v = fmaxf(fmaxf(sacc[0][r], sacc[1][r]), fmaxf(sacc[2][r], sacc[3][r]));
            v = fmaxf(v, __shfl_xor(v, 1, 16));
            v = fmaxf(v, __shfl_xor(v, 2, 16));
            v = fmaxf(v, __shfl_xor(v, 4, 16));
            v = fmaxf(v, __shfl_xor(v, 8, 16));
            vmax[r] = v;
        }
        bool grow = (vmax[0] > mrow[0] + 8.f) || (vmax[1] > mrow[1] + 8.f) ||
                    (vmax[2] > mrow[2] + 8.f) || (vmax[3] > mrow[3] + 8.f);
        if (__any(grow)) {
            #pragma unroll
            for (int r = 0; r < 4; ++r) {
                float mn = fmaxf(mrow[r], vmax[r]);
                float sf = exp2f(mrow[r] - mn);
                mrow[r] = mn;
                lrow[r] *= sf;
                #pragma unroll
                for (int n = 0; n < 4; ++n) oacc[n][r] *= sf;
            }
        }
        float rs[4] = {0.f, 0.f, 0.f, 0.f};
        #pragma unroll
        for (int n = 0; n < 4; ++n) {
            #pragma unroll
            for (int r = 0; r < 4; ++r) {
                float p = exp2f(sacc[n][r] - mrow[r]);
                rs[r] += p;
                int prow = g * 4 + r;
                int sl = (n * 2 + (l15 >> 3)) ^ (prow & 7);   // swizzled 16B slot
                lP[w][prow * 64 + sl * 8 + (l15 & 7)] = __float2bfloat16(p);
            }
        }
        #pragma unroll
        for (int r = 0; r < 4; ++r) {
            rs[r] += __shfl_xor(rs[r], 1, 16);
            rs[r] += __shfl_xor(rs[r], 2, 16);
            rs[r] += __shfl_xor(rs[r], 4, 16);
            rs[r] += __shfl_xor(rs[r], 8, 16);
            lrow[r] += rs[r];
        }

        // O += P @ V
        __builtin_amdgcn_s_setprio(1);
        #pragma unroll
        for (int ks = 0; ks < 2; ++ks) {
            int idx = l15 * 64 + (((ks * 4 + g) ^ (l15 & 7)) * 8);
            short8 pa = *reinterpret_cast<const short8*>(&lP[w][idx]);
            #pragma unroll
            for (int n = 0; n < 4; ++n) {
                int vrow = n * 16 + l15;
                int vidx = vrow * 64 + (((ks * 4 + g) ^ (vrow & 7)) * 8);
                short8 vf = *reinterpret_cast<const short8*>(&lV[cur][vidx]);
                oacc[n] = MFMA16(pa, vf, oacc[n]);
            }
        }
        __builtin_amdgcn_s_setprio(0);

        BARSYNC();   // next tile's staging (issued at top) is now complete
        cur ^= 1;
    }

    #pragma unroll
    for (int n = 0; n < 4; ++n) {
        int dcol = h * 64 + n * 16 + l15;
        #pragma unroll
        for (int r = 0; r < 4; ++r) {
            int row = b * SS + q0 + w * 16 + g * 4 + r;
            AO[row * SD + dcol] = __float2bfloat16(oacc[n][r] / lrow[r]);
        }
    }
}

extern "C" void kernel_launch(void* const* d_in, const int* in_sizes, int n_in,
                              void* d_out, int out_size, void* d_ws, size_t ws_size,
                              hipStream_t stream) {
    const float* x  = (const float*)d_in[0];
    const float* wq = (const float*)d_in[1];
    const float* wk = (const float*)d_in[2];
    const float* wv = (const float*)d_in[3];
    const float* wo = (const float*)d_in[4];
    float* out = (float*)d_out;

    bf16* xb   = (bf16*)d_ws;              // 3,145,728 elems
    bf16* wqkv = xb + SM * SD;             // 1,769,472
    bf16* wob  = wqkv + 3 * SD * SD;       // 589,824
    bf16* qkv  = wob + SD * SD;            // 3 * 3,145,728 (Q, K, V^T)
    bf16* ao   = qkv + 3 * BHSD;           // 3,145,728
    // total ~36.2 MB of d_ws

    const int NX = SM * SD;        // 3145728
    const int NW = SD * SD;        // 589824
    cvt_f32_bf16_x4<<<NX / 1024, 256, 0, stream>>>((const float4*)x,  (uint64_t*)xb,          NX / 4);
    cvt_f32_bf16_x4<<<NW / 1024, 256, 0, stream>>>((const float4*)wq, (uint64_t*)wqkv,        NW / 4);
    cvt_f32_bf16_x4<<<NW / 1024, 256, 0, stream>>>((const float4*)wk, (uint64_t*)(wqkv + NW), NW / 4);
    cvt_f32_bf16_x4<<<NW / 1024, 256, 0, stream>>>((const float4*)wv, (uint64_t*)(wqkv + 2 * NW), NW / 4);
    cvt_f32_bf16_x4<<<NW / 1024, 256, 0, stream>>>((const float4*)wo, (uint64_t*)wob,         NW / 4);

    gemm_bt<0><<<dim3(2304 / 128, SM / 128), 256, 0, stream>>>(xb, wqkv, (void*)qkv, SD);
    attn_kernel<<<768, 256, 0, stream>>>(qkv, qkv + BHSD, qkv + 2 * BHSD, ao);
    gemm_bt<1><<<dim3(SD / 128, SM / 128), 256, 0, stream>>>(ao, wob, (void*)out, SD);
}

// Round 3
// 157.394 us; speedup vs baseline: 1.0598x; 1.0021x over previous
//
#include <hip/hip_runtime.h>
#include <hip/hip_bf16.h>
#include <stdint.h>

typedef __hip_bfloat16 bf16;
typedef __attribute__((ext_vector_type(8))) short short8;
typedef __attribute__((ext_vector_type(4))) float f32x4;

#define MFMA16(A, B, C) __builtin_amdgcn_mfma_f32_16x16x32_bf16(A, B, C, 0, 0, 0)

// ---- constants ----
#define SB 2
#define SS 2048
#define SD 768
#define SH 12
#define SDK 64
#define SM (SB*SS)            // 4096 rows
#define BHSD (SB*SH*SS*SDK)   // 3145728 elems per Q/K/V
// (1/sqrt(64)) * log2(e) folded into Q at projection time -> attn works in exp2 domain
#define QSCALE 0.18033688011112042f

__device__ __forceinline__ void gload_lds16(const bf16* g, bf16* l) {
    __builtin_amdgcn_global_load_lds(
        (const __attribute__((address_space(1))) void*)(g),
        (__attribute__((address_space(3))) void*)(l),
        16, 0, 0);
}

// vmcnt(0) drain + raw barrier + scheduling fence (T3-min 2-phase recipe)
#define BARSYNC() do { \
    asm volatile("s_waitcnt vmcnt(0)" ::: "memory"); \
    __builtin_amdgcn_s_barrier(); \
    __builtin_amdgcn_sched_barrier(0); \
} while (0)

// ---- f32 -> bf16 convert, 4 elems/thread ----
__global__ void cvt_f32_bf16_x4(const float4* __restrict__ s, uint64_t* __restrict__ d, int n4) {
    int i = blockIdx.x * blockDim.x + threadIdx.x;
    if (i >= n4) return;
    float4 v = s[i];
    union { bf16 h[4]; uint64_t u; } p;
    p.h[0] = __float2bfloat16(v.x);
    p.h[1] = __float2bfloat16(v.y);
    p.h[2] = __float2bfloat16(v.z);
    p.h[3] = __float2bfloat16(v.w);
    d[i] = p.u;
}

// ---- MFMA GEMM: Y = A[M,K] @ Bw[N,K]^T, 128x128 tile, BK=64 ----
// EPI==0: scatter to Q/K/V (Out = qkv base, N==2304). V stored transposed [bh][dk][s].
//         Q additionally scaled by QSCALE (softmax works in exp2 domain).
// EPI==1: f32 row-major [M,768] to Out.
template<int EPI>
__global__ __launch_bounds__(256) void gemm_bt(const bf16* __restrict__ A,
                                               const bf16* __restrict__ Bw,
                                               void* __restrict__ Out,
                                               int K) {
    __shared__ bf16 lA[128 * 64];
    __shared__ bf16 lB[128 * 64];
    const int tid  = threadIdx.x;
    const int lane = tid & 63;
    const int wid  = tid >> 6;
    const int wr = wid >> 1, wc = wid & 1;
    const int m0 = blockIdx.y * 128, n0 = blockIdx.x * 128;
    const int g = lane >> 4, l15 = lane & 15;
    const int srow = lane >> 3, slot = lane & 7;

    f32x4 acc[4][4] = {};

    for (int kt = 0; kt < K; kt += 64) {
        __syncthreads();
        #pragma unroll
        for (int p = 0; p < 4; ++p) {
            int c = wid * 4 + p;              // chunk 0..15, 8 rows each
            int row = c * 8 + srow;
            int colsw = (slot ^ (row & 7)) * 8;   // pre-swizzled source col
            gload_lds16(A  + (m0 + row) * K + kt + colsw, &lA[c * 512]);
            gload_lds16(Bw + (n0 + row) * K + kt + colsw, &lB[c * 512]);
        }
        __syncthreads();
        #pragma unroll
        for (int ks = 0; ks < 2; ++ks) {
            short8 af[4], bfv[4];
            #pragma unroll
            for (int m = 0; m < 4; ++m) {
                int row = wr * 64 + m * 16 + l15;
                int idx = row * 64 + (((ks * 4 + g) ^ (row & 7)) * 8);
                af[m] = *reinterpret_cast<const short8*>(&lA[idx]);
            }
            #pragma unroll
            for (int n = 0; n < 4; ++n) {
                int row = wc * 64 + n * 16 + l15;
                int idx = row * 64 + (((ks * 4 + g) ^ (row & 7)) * 8);
                bfv[n] = *reinterpret_cast<const short8*>(&lB[idx]);
            }
            #pragma unroll
            for (int m = 0; m < 4; ++m)
                #pragma unroll
                for (int n = 0; n < 4; ++n)
                    acc[m][n] = MFMA16(af[m], bfv[n], acc[m][n]);
        }
    }

    #pragma unroll
    for (int m = 0; m < 4; ++m) {
        #pragma unroll
        for (int n = 0; n < 4; ++n) {
            int col = n0 + wc * 64 + n * 16 + l15;
            #pragma unroll
            for (int r = 0; r < 4; ++r) {
                int row = m0 + wr * 64 + m * 16 + g * 4 + r;
                float v = acc[m][n][r];
                if constexpr (EPI == 0) {
                    int which = (col >= 1536) ? 2 : (col >= 768 ? 1 : 0);
                    int e = col - which * 768;
                    int h = e >> 6, d = e & 63;
                    int b = row >> 11, s = row & 2047;
                    int bh = b * SH + h;
                    bf16* dst = (bf16*)Out;
                    int idx;
                    if (which == 2) idx = 2 * BHSD + (bh * 64 + d) * SS + s;   // V^T [bh][dk][s]
                    else            idx = which * BHSD + (bh * SS + s) * 64 + d;
                    if (which == 0) v *= QSCALE;
                    dst[idx] = __float2bfloat16(v);
                } else {
                    ((float*)Out)[row * SD + col] = v;
                }
            }
        }
    }
}

// ---- flash attention: 768 blocks (XCD-swizzled), 4 waves, QBLK=64, KVBLK=64 ----
// Double-buffered K/V staging (T3-min 2-phase), defer-max (T13), setprio (T5).
__global__ __launch_bounds__(256) void attn_kernel(const bf16* __restrict__ Qb,
                                                   const bf16* __restrict__ Kb,
                                                   const bf16* __restrict__ Vtb,
                                                   bf16* __restrict__ AO) {
    __shared__ bf16 lK[2][64 * 64];
    __shared__ bf16 lV[2][64 * 64];   // V^T tile: [dk][kv]
    __shared__ bf16 lP[4][16 * 64];   // per-wave P scratch

    // bijective XCD swizzle: 768 = 8 XCDs x 96; same-bh blocks cluster per XCD,
    // heavy q-tiles first within each XCD.
    const int orig = blockIdx.x;
    const int wgid = (orig & 7) * 96 + (orig >> 3);
    const int bh = wgid >> 5;
    const int qt = 31 - (wgid & 31);

    const int b = bh / SH, h = bh - b * SH;
    const int tid = threadIdx.x, lane = tid & 63, w = tid >> 6;
    const int g = lane >> 4, l15 = lane & 15;
    const int q0 = qt * 64;
    const int srow = lane >> 3, slot = lane & 7;

    const bf16* Qh = Qb + bh * SS * 64;
    const bf16* Kh = Kb + bh * SS * 64;
    const bf16* Vh = Vtb + bh * 64 * SS;

    short8 qf[2];
    #pragma unroll
    for (int ks = 0; ks < 2; ++ks)
        qf[ks] = *reinterpret_cast<const short8*>(Qh + (q0 + w * 16 + l15) * 64 + ks * 32 + g * 8);

    f32x4 oacc[4] = {};
    float mrow[4], lrow[4];
    #pragma unroll
    for (int r = 0; r < 4; ++r) { mrow[r] = -1e30f; lrow[r] = 0.f; }

    auto STAGE = [&](int buf, int kt) {
        #pragma unroll
        for (int p = 0; p < 2; ++p) {
            int c = w * 2 + p;               // chunk 0..7, 8 rows each
            int row = c * 8 + srow;
            int colsw = (slot ^ (row & 7)) * 8;
            gload_lds16(Kh + (kt * 64 + row) * 64 + colsw, &lK[buf][c * 512]);
            gload_lds16(Vh + row * SS + kt * 64 + colsw, &lV[buf][c * 512]);
        }
    };

    // prologue: stage tile 0
    STAGE(0, 0);
    BARSYNC();

    int cur = 0;
    for (int kt = 0; kt <= qt; ++kt) {
        // issue next tile's loads FIRST (they fly under this tile's compute)
        if (kt < qt) STAGE(cur ^ 1, kt + 1);

        // S = Q @ K^T   (16 x 64 per wave) — Q pre-scaled, S in exp2 domain
        f32x4 sacc[4] = {};
        __builtin_amdgcn_s_setprio(1);
        #pragma unroll
        for (int ks = 0; ks < 2; ++ks) {
            #pragma unroll
            for (int n = 0; n < 4; ++n) {
                int row = n * 16 + l15;
                int idx = row * 64 + (((ks * 4 + g) ^ (row & 7)) * 8);
                short8 kf = *reinterpret_cast<const short8*>(&lK[cur][idx]);
                sacc[n] = MFMA16(qf[ks], kf, sacc[n]);
            }
        }
        __builtin_amdgcn_s_setprio(0);

        if (kt == qt) {   // diagonal tile: causal mask
            #pragma unroll
            for (int n = 0; n < 4; ++n) {
                int kcol = kt * 64 + n * 16 + l15;
                #pragma unroll
                for (int r = 0; r < 4; ++r) {
                    int qrow = q0 + w * 16 + g * 4 + r;
                    if (kcol > qrow) sacc[n][r] = -1e30f;
                }
            }
        }

        // ---- online softmax (exp2 domain), defer-max THR=8 ----
        float vmax[4];
        #pragma unroll
        for (int r = 0; r < 4; ++r) {
            float v = fmaxf(fmaxf(sacc[0][r], sacc[1][r]), fmaxf(sacc[2][r], sacc[3][r]));
            v = fmaxf(v, __shfl_xor(v, 1, 16));
            v = fmaxf(v, __shfl_xor(v, 2, 16));
            v = fmaxf(v, __shfl_xor(v, 4, 16));
            v = fmaxf(v, __shfl_xor(v, 8, 16));
            vmax[r] = v;
        }
        bool grow = (vmax[0] > mrow[0] + 8.f) || (vmax[1] > mrow[1] + 8.f) ||
                    (vmax[2] > mrow[2] + 8.f) || (vmax[3] > mrow[3] + 8.f);
        if (__any(grow)) {
            #pragma unroll
            for (int r = 0; r < 4; ++r) {
                float mn = fmaxf(mrow[r], vmax[r]);
                float sf = exp2f(mrow[r] - mn);
                mrow[r] = mn;
                lrow[r] *= sf;
                #pragma unroll
                for (int n = 0; n < 4; ++n) oacc[n][r] *= sf;
            }
        }
        float rs[4] = {0.f, 0.f, 0.f, 0.f};
        #pragma unroll
        for (int n = 0; n < 4; ++n) {
            #pragma unroll
            for (int r = 0; r < 4; ++r) {
                float p = exp2f(sacc[n][r] - mrow[r]);
                rs[r] += p;
                int prow = g * 4 + r;
                int sl = (n * 2 + (l15 >> 3)) ^ (prow & 7);   // swizzled 16B slot
                lP[w][prow * 64 + sl * 8 + (l15 & 7)] = __float2bfloat16(p);
            }
        }
        #pragma unroll
        for (int r = 0; r < 4; ++r) {
            rs[r] += __shfl_xor(rs[r], 1, 16);
            rs[r] += __shfl_xor(rs[r], 2, 16);
            rs[r] += __shfl_xor(rs[r], 4, 16);
            rs[r] += __shfl_xor(rs[r], 8, 16);
            lrow[r] += rs[r];
        }

        // O += P @ V
        __builtin_amdgcn_s_setprio(1);
        #pragma unroll
        for (int ks = 0; ks < 2; ++ks) {
            int idx = l15 * 64 + (((ks * 4 + g) ^ (l15 & 7)) * 8);
            short8 pa = *reinterpret_cast<const short8*>(&lP[w][idx]);
            #pragma unroll
            for (int n = 0; n < 4; ++n) {
                int vrow = n * 16 + l15;
                int vidx = vrow * 64 + (((ks * 4 + g) ^ (vrow & 7)) * 8);
                short8 vf = *reinterpret_cast<const short8*>(&lV[cur][vidx]);
                oacc[n] = MFMA16(pa, vf, oacc[n]);
            }
        }
        __builtin_amdgcn_s_setprio(0);

        BARSYNC();   // next tile's staging (issued at top) is now complete
        cur ^= 1;
    }

    #pragma unroll
    for (int n = 0; n < 4; ++n) {
        int dcol = h * 64 + n * 16 + l15;
        #pragma unroll
        for (int r = 0; r < 4; ++r) {
            int row = b * SS + q0 + w * 16 + g * 4 + r;
            AO[row * SD + dcol] = __float2bfloat16(oacc[n][r] / lrow[r]);
        }
    }
}

extern "C" void kernel_launch(void* const* d_in, const int* in_sizes, int n_in,
                              void* d_out, int out_size, void* d_ws, size_t ws_size,
                              hipStream_t stream) {
    const float* x  = (const float*)d_in[0];
    const float* wq = (const float*)d_in[1];
    const float* wk = (const float*)d_in[2];
    const float* wv = (const float*)d_in[3];
    const float* wo = (const float*)d_in[4];
    float* out = (float*)d_out;

    bf16* xb   = (bf16*)d_ws;              // 3,145,728 elems
    bf16* wqkv = xb + SM * SD;             // 1,769,472
    bf16* wob  = wqkv + 3 * SD * SD;       // 589,824
    bf16* qkv  = wob + SD * SD;            // 3 * 3,145,728 (Q, K, V^T)
    bf16* ao   = qkv + 3 * BHSD;           // 3,145,728
    // total ~36.2 MB of d_ws

    const int NX = SM * SD;        // 3145728
    const int NW = SD * SD;        // 589824
    cvt_f32_bf16_x4<<<NX / 1024, 256, 0, stream>>>((const float4*)x,  (uint64_t*)xb,          NX / 4);
    cvt_f32_bf16_x4<<<NW / 1024, 256, 0, stream>>>((const float4*)wq, (uint64_t*)wqkv,        NW / 4);
    cvt_f32_bf16_x4<<<NW / 1024, 256, 0, stream>>>((const float4*)wk, (uint64_t*)(wqkv + NW), NW / 4);
    cvt_f32_bf16_x4<<<NW / 1024, 256, 0, stream>>>((const float4*)wv, (uint64_t*)(wqkv + 2 * NW), NW / 4);
    cvt_f32_bf16_x4<<<NW / 1024, 256, 0, stream>>>((const float4*)wo, (uint64_t*)wob,         NW / 4);

    gemm_bt<0><<<dim3(2304 / 128, SM / 128), 256, 0, stream>>>(xb, wqkv, (void*)qkv, SD);
    attn_kernel<<<768, 256, 0, stream>>>(qkv, qkv + BHSD, qkv + 2 * BHSD, ao);
    gemm_bt<1><<<dim3(SD / 128, SM / 128), 256, 0, stream>>>(ao, wob, (void*)out, SD);
}